// Round 9
// baseline (125.184 us; speedup 1.0000x reference)
//
#include <hip/hip_runtime.h>

// Problem constants
#define B_     64
#define L_     1024
#define D_     1280   // 320 float4
#define H1_    640
#define H2_    320
#define NSPLIT 32     // per-batch even-split stripes for pooling

// ---------------- Kernel 1: per-batch even-split stripe partial sums ----------------
// BYTE-IDENTICAL to R7/R8. (R8 probe measured this kernel at ~25.5 us — at the
// HBM/L3 ceiling for its 167 MB read.)
__global__ void pool_partial(const float* __restrict__ rep, const int* __restrict__ blen,
                             float* __restrict__ part) {
    const int s   = blockIdx.x;     // stripe
    const int b   = blockIdx.y;     // batch
    const int tid = threadIdx.x;    // 0..319 (float4 lane)
    const int n   = blen[b] - 2;    // valid rows (>=1)

    const int l0 = 1 + (s * n) / NSPLIT;
    const int l1 = 1 + ((s + 1) * n) / NSPLIT;

    float4 acc = make_float4(0.f, 0.f, 0.f, 0.f);
    const float4* base = (const float4*)rep + (size_t)b * L_ * (D_ / 4) + tid;
    #pragma unroll 8
    for (int l = l0; l < l1; ++l) {
        float4 v = base[(size_t)l * (D_ / 4)];
        acc.x += v.x; acc.y += v.y; acc.z += v.z; acc.w += v.w;
    }
    // always write (empty stripes contribute zeros)
    ((float4*)part)[((size_t)b * NSPLIT + s) * (D_ / 4) + tid] = acc;
}

// ---------------- Kernel 2: per-batch fused tail (BYTE-IDENTICAL to R7) ----------
// Launched TWICE this round as a timing probe: pure function of part/weights,
// so the duplicate writes identical values to out (deterministic, graph-safe).
// dur_us(R9) - dur_us(R7) == this kernel's duration.
__global__ void fused_tail(const float* __restrict__ part, const int* __restrict__ blen,
                           const float* __restrict__ W1, const float* __restrict__ b1,
                           const float* __restrict__ W2, const float* __restrict__ b2,
                           const float* __restrict__ W3, const float* __restrict__ b3,
                           float* __restrict__ out) {
    const int b   = blockIdx.x;
    const int tid = threadIdx.x;   // 0..319

    __shared__ float prow[D_];     // 5 KB
    __shared__ float hrow[H1_];    // 2.5 KB
    __shared__ float erow[H2_];    // 1.25 KB

    // ---- Phase A: stripe reduce; thread owns float4 column tid ----
    {
        int n = blen[b] - 2; if (n < 1) n = 1;
        const float inv = 1.0f / (float)n;
        const float4* p = (const float4*)part + (size_t)b * NSPLIT * (D_ / 4) + tid;
        float4 a = make_float4(0.f, 0.f, 0.f, 0.f);
        #pragma unroll
        for (int s = 0; s < NSPLIT; ++s) {
            float4 v = p[(size_t)s * (D_ / 4)];
            a.x += v.x; a.y += v.y; a.z += v.z; a.w += v.w;
        }
        ((float4*)prow)[tid] = make_float4(a.x * inv, a.y * inv, a.z * inv, a.w * inv);
    }
    __syncthreads();

    // ---- Phase B: hrow = relu(prow @ W1 + b1); thread owns cols tid, tid+320 ----
    {
        const int j1 = tid, j2 = tid + 320;
        float s1a = 0.f, s1b = 0.f, s2a = 0.f, s2b = 0.f;
        for (int k = 0; k < D_; k += 4) {
            const float4 pv = *(const float4*)&prow[k];          // wave-uniform broadcast
            const float* w = W1 + (size_t)k * H1_;
            s1a = fmaf(pv.x, w[j1],            s1a);
            s1b = fmaf(pv.y, w[H1_ + j1],      s1b);
            s1a = fmaf(pv.z, w[2 * H1_ + j1],  s1a);
            s1b = fmaf(pv.w, w[3 * H1_ + j1],  s1b);
            s2a = fmaf(pv.x, w[j2],            s2a);
            s2b = fmaf(pv.y, w[H1_ + j2],      s2b);
            s2a = fmaf(pv.z, w[2 * H1_ + j2],  s2a);
            s2b = fmaf(pv.w, w[3 * H1_ + j2],  s2b);
        }
        hrow[j1] = fmaxf(s1a + s1b + b1[j1], 0.f);
        hrow[j2] = fmaxf(s2a + s2b + b1[j2], 0.f);
    }
    __syncthreads();

    // ---- Phase C: erow = relu(hrow @ W2 + b2); thread owns col tid ----
    {
        const int j = tid;
        float a0 = 0.f, a1 = 0.f;
        for (int k = 0; k < H1_; k += 4) {
            const float4 hv = *(const float4*)&hrow[k];
            const float* w = W2 + (size_t)k * H2_ + j;
            a0 = fmaf(hv.x, w[0],        a0);
            a1 = fmaf(hv.y, w[H2_],      a1);
            a0 = fmaf(hv.z, w[2 * H2_],  a0);
            a1 = fmaf(hv.w, w[3 * H2_],  a1);
        }
        const float e = fmaxf(a0 + a1 + b2[j], 0.f);
        erow[j] = e;
        out[128 + (size_t)b * H2_ + j] = e;
    }
    __syncthreads();

    // ---- Phase D: y = erow @ W3 + b3 (two waves, shuffle reduce) ----
    if (tid < 128) {
        const int o = tid >> 6, lane = tid & 63;
        float s = 0.f;
        for (int j = lane; j < H2_; j += 64)
            s = fmaf(erow[j], W3[(size_t)j * 2 + o], s);
        #pragma unroll
        for (int off = 32; off >= 1; off >>= 1)
            s += __shfl_down(s, off, 64);
        if (lane == 0) out[(size_t)b * 2 + o] = s + b3[o];
    }
}

extern "C" void kernel_launch(void* const* d_in, const int* in_sizes, int n_in,
                              void* d_out, int out_size, void* d_ws, size_t ws_size,
                              hipStream_t stream) {
    const float* rep  = (const float*)d_in[0];
    const int*   blen = (const int*)  d_in[1];
    const float* W1   = (const float*)d_in[2];
    const float* b1   = (const float*)d_in[3];
    const float* W2   = (const float*)d_in[4];
    const float* b2   = (const float*)d_in[5];
    const float* W3   = (const float*)d_in[6];
    const float* b3   = (const float*)d_in[7];
    float* out = (float*)d_out;

    // workspace: part = B_*NSPLIT*D_ floats (10.5 MB)
    float* part = (float*)d_ws;

    // TIMING PROBE: fused_tail launched twice (identical output).
    // dur_us(R9) - dur_us(R7) == fused_tail duration.
    pool_partial<<<dim3(NSPLIT, B_), 320, 0, stream>>>(rep, blen, part);
    fused_tail  <<<B_, 320, 0, stream>>>(part, blen, W1, b1, W2, b2, W3, b3, out);
    fused_tail  <<<B_, 320, 0, stream>>>(part, blen, W1, b1, W2, b2, W3, b3, out);
}

// Round 10
// 60.923 us; speedup vs baseline: 2.0548x; 2.0548x over previous
//
#include <hip/hip_runtime.h>

// Problem constants
#define B_     64
#define L_     1024
#define D_     1280   // 320 float4
#define H1_    640
#define H2_    320
#define NSPLIT 32     // per-batch even-split stripes for pooling
#define KS_    16     // k-splits for mlp1
#define KC_    80     // 1280/16
#define NJT_   10     // W1 j-tiles of 64
#define NJT2_  5      // W2 j-tiles of 64

// ---------------- Kernel 1: per-batch even-split stripe partial sums ----------------
// BYTE-IDENTICAL to R7/R8/R9 (probe-measured at ~25.5us warm — HBM ceiling).
__global__ void pool_partial(const float* __restrict__ rep, const int* __restrict__ blen,
                             float* __restrict__ part) {
    const int s   = blockIdx.x;     // stripe
    const int b   = blockIdx.y;     // batch
    const int tid = threadIdx.x;    // 0..319 (float4 lane)
    const int n   = blen[b] - 2;    // valid rows (>=1)

    const int l0 = 1 + (s * n) / NSPLIT;
    const int l1 = 1 + ((s + 1) * n) / NSPLIT;

    float4 acc = make_float4(0.f, 0.f, 0.f, 0.f);
    const float4* base = (const float4*)rep + (size_t)b * L_ * (D_ / 4) + tid;
    #pragma unroll 8
    for (int l = l0; l < l1; ++l) {
        float4 v = base[(size_t)l * (D_ / 4)];
        acc.x += v.x; acc.y += v.y; acc.z += v.z; acc.w += v.w;
    }
    ((float4*)part)[((size_t)b * NSPLIT + s) * (D_ / 4) + tid] = acc;
}

// ---------------- Kernel 2: stripe reduce -> pooled ----------------
__global__ void pool_reduce(const float* __restrict__ part, const int* __restrict__ blen,
                            float* __restrict__ pooled) {
    const int b   = blockIdx.x;
    const int tid = threadIdx.x;    // 0..319
    int n = blen[b] - 2; if (n < 1) n = 1;
    const float inv = 1.0f / (float)n;
    const float4* p = (const float4*)part + (size_t)b * NSPLIT * (D_ / 4) + tid;
    float4 a = make_float4(0.f, 0.f, 0.f, 0.f);
    #pragma unroll
    for (int s = 0; s < NSPLIT; ++s) {
        float4 v = p[(size_t)s * (D_ / 4)];
        a.x += v.x; a.y += v.y; a.z += v.z; a.w += v.w;
    }
    ((float4*)pooled)[(size_t)b * (D_ / 4) + tid] =
        make_float4(a.x * inv, a.y * inv, a.z * inv, a.w * inv);
}

// ---------------- Kernel 3: mlp1 partials (W1 read once grid-wide) ----------------
// grid (NJT_, KS_) = 160 blocks x 256 thr. Thread owns 16 batches x 1 column.
__global__ void mlp1_partial(const float* __restrict__ pooled, const float* __restrict__ W1,
                             float* __restrict__ hpart) {
    const int jt  = blockIdx.x;     // 0..9
    const int ks  = blockIdx.y;     // 0..15
    const int tid = threadIdx.x;    // 0..255
    const int jl  = tid & 63;
    const int b0  = (tid >> 6) * 16;
    const int k0  = ks * KC_;
    const int j0  = jt * 64;

    __shared__ float pl[B_][KC_];   // pooled k-slice (20 KB)
    for (int e = tid; e < B_ * (KC_ / 4); e += 256) {
        const int b   = e / (KC_ / 4);
        const int kk4 = e % (KC_ / 4);
        float4 v = ((const float4*)pooled)[(size_t)b * (D_ / 4) + (k0 / 4) + kk4];
        *(float4*)&pl[b][kk4 * 4] = v;
    }
    __syncthreads();

    float acc[16];
    #pragma unroll
    for (int r = 0; r < 16; ++r) acc[r] = 0.f;

    const float* w1p = W1 + (size_t)k0 * H1_ + j0 + jl;
    for (int kk = 0; kk < KC_; kk += 4) {
        const float w0 = w1p[(size_t)(kk + 0) * H1_];
        const float w1 = w1p[(size_t)(kk + 1) * H1_];
        const float w2 = w1p[(size_t)(kk + 2) * H1_];
        const float w3 = w1p[(size_t)(kk + 3) * H1_];
        #pragma unroll
        for (int r = 0; r < 16; ++r) {
            float4 pv = *(const float4*)&pl[b0 + r][kk];
            acc[r] = fmaf(pv.x, w0, acc[r]);
            acc[r] = fmaf(pv.y, w1, acc[r]);
            acc[r] = fmaf(pv.z, w2, acc[r]);
            acc[r] = fmaf(pv.w, w3, acc[r]);
        }
    }
    float* hp = hpart + (size_t)ks * B_ * H1_;
    #pragma unroll
    for (int r = 0; r < 16; ++r)
        hp[(size_t)(b0 + r) * H1_ + j0 + jl] = acc[r];
}

// ---------------- Kernel 4: h-reduce + W2 j-slice -> emb ----------------
// grid (NJT2_, B_) = 320 blocks x 256 thr. Block (jt,b): reduce hrow[b] from
// hpart (40 KB, 5x redundant - L3), then emb cols j0..j0+63 with a 160 KB W2
// slice. Thread = (jl = tid&63, kq = tid>>6) k-split; LDS combine.
__global__ void mlp2(const float* __restrict__ hpart, const float* __restrict__ b1,
                     const float* __restrict__ W2, const float* __restrict__ b2,
                     float* __restrict__ out) {
    const int jt  = blockIdx.x;     // 0..4
    const int b   = blockIdx.y;     // 0..63
    const int tid = threadIdx.x;    // 0..255
    const int jl  = tid & 63;
    const int kq  = tid >> 6;       // 0..3
    const int j   = jt * 64 + jl;

    __shared__ float hrow[H1_];     // 2.56 KB
    __shared__ float pt[4][64];     // 1 KB

    // reduce h[b][j'] for j' = tid, tid+256, ... (coalesced per ks)
    for (int jj = tid; jj < H1_; jj += 256) {
        float s = b1[jj];
        #pragma unroll
        for (int ks = 0; ks < KS_; ++ks)
            s += hpart[((size_t)ks * B_ + b) * H1_ + jj];
        hrow[jj] = fmaxf(s, 0.f);
    }
    __syncthreads();

    // emb partial over k in [kq*160, kq*160+160)
    float a0 = 0.f, a1 = 0.f, a2 = 0.f, a3 = 0.f;
    const int kbeg = kq * (H1_ / 4);
    const float* w = W2 + (size_t)kbeg * H2_ + j;
    #pragma unroll 4
    for (int k = 0; k < H1_ / 4; k += 4) {
        const float4 hv = *(const float4*)&hrow[kbeg + k];   // wave-uniform broadcast
        a0 = fmaf(hv.x, w[(size_t)(k + 0) * H2_], a0);
        a1 = fmaf(hv.y, w[(size_t)(k + 1) * H2_], a1);
        a2 = fmaf(hv.z, w[(size_t)(k + 2) * H2_], a2);
        a3 = fmaf(hv.w, w[(size_t)(k + 3) * H2_], a3);
    }
    pt[kq][jl] = (a0 + a1) + (a2 + a3);
    __syncthreads();

    if (tid < 64) {
        const float e = fmaxf(pt[0][jl] + pt[1][jl] + pt[2][jl] + pt[3][jl] + b2[j], 0.f);
        out[128 + (size_t)b * H2_ + j] = e;
    }
}

// ---------------- Kernel 5: y = emb @ W3 + b3 ----------------
// 64 blocks x 64 thr; emb read back from out (written by mlp2, same stream).
__global__ void mlp3(const float* __restrict__ out_emb, const float* __restrict__ W3,
                     const float* __restrict__ b3, float* __restrict__ out) {
    const int b    = blockIdx.x;
    const int lane = threadIdx.x;   // 0..63
    float s0 = 0.f, s1 = 0.f;
    #pragma unroll
    for (int i = 0; i < H2_ / 64; ++i) {
        const int jj = lane + i * 64;
        const float e = out_emb[128 + (size_t)b * H2_ + jj];
        s0 = fmaf(e, W3[(size_t)jj * 2 + 0], s0);
        s1 = fmaf(e, W3[(size_t)jj * 2 + 1], s1);
    }
    #pragma unroll
    for (int off = 32; off >= 1; off >>= 1) {
        s0 += __shfl_xor(s0, off, 64);
        s1 += __shfl_xor(s1, off, 64);
    }
    if (lane == 0) {
        out[(size_t)b * 2 + 0] = s0 + b3[0];
        out[(size_t)b * 2 + 1] = s1 + b3[1];
    }
}

extern "C" void kernel_launch(void* const* d_in, const int* in_sizes, int n_in,
                              void* d_out, int out_size, void* d_ws, size_t ws_size,
                              hipStream_t stream) {
    const float* rep  = (const float*)d_in[0];
    const int*   blen = (const int*)  d_in[1];
    const float* W1   = (const float*)d_in[2];
    const float* b1   = (const float*)d_in[3];
    const float* W2   = (const float*)d_in[4];
    const float* b2   = (const float*)d_in[5];
    const float* W3   = (const float*)d_in[6];
    const float* b3   = (const float*)d_in[7];
    float* out = (float*)d_out;

    // workspace layout (floats):
    //   part   B_*NSPLIT*D_ = 2,621,440  (10.5 MB)
    //   pooled B_*D_        =    81,920
    //   hpart  KS_*B_*H1_   =   655,360
    float* ws     = (float*)d_ws;
    float* part   = ws;
    float* pooled = part + (size_t)B_ * NSPLIT * D_;
    float* hpart  = pooled + (size_t)B_ * D_;

    pool_partial<<<dim3(NSPLIT, B_), 320, 0, stream>>>(rep, blen, part);
    pool_reduce <<<B_, 320, 0, stream>>>(part, blen, pooled);
    mlp1_partial<<<dim3(NJT_, KS_), 256, 0, stream>>>(pooled, W1, hpart);
    mlp2        <<<dim3(NJT2_, B_), 256, 0, stream>>>(hpart, b1, W2, b2, out);
    mlp3        <<<B_, 64, 0, stream>>>(out, W3, b3, out);
}

// Round 11
// 50.724 us; speedup vs baseline: 2.4679x; 1.2011x over previous
//
#include <hip/hip_runtime.h>

// Problem constants
#define B_     64
#define L_     1024
#define D_     1280   // 320 float4
#define H1_    640
#define H2_    320
#define NSPLIT 32     // per-batch even-split stripes for pooling
#define KS_    16     // k-splits for mlp1
#define KC_    80     // 1280/16
#define NJT_   10     // W1 j-tiles of 64
#define NJT2_  5      // W2 j-tiles of 64

// ---------------- Kernel 1: per-batch even-split stripe partial sums ----------------
// BYTE-IDENTICAL to R7-R10 (probe-measured at ~25.5us warm — HBM ceiling).
__global__ void pool_partial(const float* __restrict__ rep, const int* __restrict__ blen,
                             float* __restrict__ part) {
    const int s   = blockIdx.x;     // stripe
    const int b   = blockIdx.y;     // batch
    const int tid = threadIdx.x;    // 0..319 (float4 lane)
    const int n   = blen[b] - 2;    // valid rows (>=1)

    const int l0 = 1 + (s * n) / NSPLIT;
    const int l1 = 1 + ((s + 1) * n) / NSPLIT;

    float4 acc = make_float4(0.f, 0.f, 0.f, 0.f);
    const float4* base = (const float4*)rep + (size_t)b * L_ * (D_ / 4) + tid;
    #pragma unroll 8
    for (int l = l0; l < l1; ++l) {
        float4 v = base[(size_t)l * (D_ / 4)];
        acc.x += v.x; acc.y += v.y; acc.z += v.z; acc.w += v.w;
    }
    ((float4*)part)[((size_t)b * NSPLIT + s) * (D_ / 4) + tid] = acc;
}

// ---------------- Kernel 2: stripe reduce -> pooled ----------------
// grid (5, B_) = 320 blocks x 64 thr: block owns 64 float4 cols of one batch.
// Whole chip active + TLP (vs R10's 64 blocks = quarter of the chip).
__global__ void pool_reduce(const float* __restrict__ part, const int* __restrict__ blen,
                            float* __restrict__ pooled) {
    const int qt  = blockIdx.x;     // col quarter-tile 0..4
    const int b   = blockIdx.y;     // batch
    const int tid = threadIdx.x;    // 0..63
    const int col = qt * 64 + tid;  // float4 column 0..319

    int n = blen[b] - 2; if (n < 1) n = 1;
    const float inv = 1.0f / (float)n;
    const float4* p = (const float4*)part + (size_t)b * NSPLIT * (D_ / 4) + col;
    float4 a = make_float4(0.f, 0.f, 0.f, 0.f);
    #pragma unroll
    for (int s = 0; s < NSPLIT; ++s) {
        float4 v = p[(size_t)s * (D_ / 4)];
        a.x += v.x; a.y += v.y; a.z += v.z; a.w += v.w;
    }
    ((float4*)pooled)[(size_t)b * (D_ / 4) + col] =
        make_float4(a.x * inv, a.y * inv, a.z * inv, a.w * inv);
}

// ---------------- Kernel 3: mlp1 partials (W1 read once grid-wide) ----------------
// grid (NJT_, KS_) = 160 blocks x 512 thr (8 waves/block = 2/SIMD).
// Thread owns 8 batches x 1 column.
__global__ void mlp1_partial(const float* __restrict__ pooled, const float* __restrict__ W1,
                             float* __restrict__ hpart) {
    const int jt  = blockIdx.x;     // 0..9
    const int ks  = blockIdx.y;     // 0..15
    const int tid = threadIdx.x;    // 0..511
    const int jl  = tid & 63;
    const int b0  = (tid >> 6) * 8; // 8 batch-groups of 8
    const int k0  = ks * KC_;
    const int j0  = jt * 64;

    __shared__ float pl[B_][KC_];   // pooled k-slice (20 KB)
    for (int e = tid; e < B_ * (KC_ / 4); e += 512) {
        const int b   = e / (KC_ / 4);
        const int kk4 = e % (KC_ / 4);
        float4 v = ((const float4*)pooled)[(size_t)b * (D_ / 4) + (k0 / 4) + kk4];
        *(float4*)&pl[b][kk4 * 4] = v;
    }
    __syncthreads();

    float acc[8];
    #pragma unroll
    for (int r = 0; r < 8; ++r) acc[r] = 0.f;

    const float* w1p = W1 + (size_t)k0 * H1_ + j0 + jl;
    for (int kk = 0; kk < KC_; kk += 4) {
        const float w0 = w1p[(size_t)(kk + 0) * H1_];
        const float w1 = w1p[(size_t)(kk + 1) * H1_];
        const float w2 = w1p[(size_t)(kk + 2) * H1_];
        const float w3 = w1p[(size_t)(kk + 3) * H1_];
        #pragma unroll
        for (int r = 0; r < 8; ++r) {
            float4 pv = *(const float4*)&pl[b0 + r][kk];
            acc[r] = fmaf(pv.x, w0, acc[r]);
            acc[r] = fmaf(pv.y, w1, acc[r]);
            acc[r] = fmaf(pv.z, w2, acc[r]);
            acc[r] = fmaf(pv.w, w3, acc[r]);
        }
    }
    float* hp = hpart + (size_t)ks * B_ * H1_;
    #pragma unroll
    for (int r = 0; r < 8; ++r)
        hp[(size_t)(b0 + r) * H1_ + j0 + jl] = acc[r];
}

// ---------------- Kernel 4: h-reduce + W2 j-slice -> emb ----------------
// grid (NJT2_, B_) = 320 blocks x 512 thr (8 waves/block).
// Thread = (jl = tid&63, kq = tid>>6): 8-way k-split of the 640-deep dot.
__global__ void mlp2(const float* __restrict__ hpart, const float* __restrict__ b1,
                     const float* __restrict__ W2, const float* __restrict__ b2,
                     float* __restrict__ out) {
    const int jt  = blockIdx.x;     // 0..4
    const int b   = blockIdx.y;     // 0..63
    const int tid = threadIdx.x;    // 0..511
    const int jl  = tid & 63;
    const int kq  = tid >> 6;       // 0..7
    const int j   = jt * 64 + jl;

    __shared__ float hrow[H1_];     // 2.56 KB
    __shared__ float pt[8][64];     // 2 KB

    // reduce h[b][jj] (coalesced per ks-slice)
    for (int jj = tid; jj < H1_; jj += 512) {
        float s = b1[jj];
        #pragma unroll
        for (int ks = 0; ks < KS_; ++ks)
            s += hpart[((size_t)ks * B_ + b) * H1_ + jj];
        hrow[jj] = fmaxf(s, 0.f);
    }
    __syncthreads();

    // emb partial over k in [kq*80, kq*80+80)
    float a0 = 0.f, a1 = 0.f, a2 = 0.f, a3 = 0.f;
    const int kbeg = kq * (H1_ / 8);
    const float* w = W2 + (size_t)kbeg * H2_ + j;
    #pragma unroll 5
    for (int k = 0; k < H1_ / 8; k += 4) {
        const float4 hv = *(const float4*)&hrow[kbeg + k];   // wave-uniform broadcast
        a0 = fmaf(hv.x, w[(size_t)(k + 0) * H2_], a0);
        a1 = fmaf(hv.y, w[(size_t)(k + 1) * H2_], a1);
        a2 = fmaf(hv.z, w[(size_t)(k + 2) * H2_], a2);
        a3 = fmaf(hv.w, w[(size_t)(k + 3) * H2_], a3);
    }
    pt[kq][jl] = (a0 + a1) + (a2 + a3);
    __syncthreads();

    if (tid < 64) {
        float e = b2[j];
        #pragma unroll
        for (int q = 0; q < 8; ++q) e += pt[q][jl];
        out[128 + (size_t)b * H2_ + j] = fmaxf(e, 0.f);
    }
}

// ---------------- Kernel 5: y = emb @ W3 + b3 ----------------
// 64 blocks x 64 thr; emb read back from out (written by mlp2, same stream).
__global__ void mlp3(const float* __restrict__ out_emb, const float* __restrict__ W3,
                     const float* __restrict__ b3, float* __restrict__ out) {
    const int b    = blockIdx.x;
    const int lane = threadIdx.x;   // 0..63
    float s0 = 0.f, s1 = 0.f;
    #pragma unroll
    for (int i = 0; i < H2_ / 64; ++i) {
        const int jj = lane + i * 64;
        const float e = out_emb[128 + (size_t)b * H2_ + jj];
        s0 = fmaf(e, W3[(size_t)jj * 2 + 0], s0);
        s1 = fmaf(e, W3[(size_t)jj * 2 + 1], s1);
    }
    #pragma unroll
    for (int off = 32; off >= 1; off >>= 1) {
        s0 += __shfl_xor(s0, off, 64);
        s1 += __shfl_xor(s1, off, 64);
    }
    if (lane == 0) {
        out[(size_t)b * 2 + 0] = s0 + b3[0];
        out[(size_t)b * 2 + 1] = s1 + b3[1];
    }
}

extern "C" void kernel_launch(void* const* d_in, const int* in_sizes, int n_in,
                              void* d_out, int out_size, void* d_ws, size_t ws_size,
                              hipStream_t stream) {
    const float* rep  = (const float*)d_in[0];
    const int*   blen = (const int*)  d_in[1];
    const float* W1   = (const float*)d_in[2];
    const float* b1   = (const float*)d_in[3];
    const float* W2   = (const float*)d_in[4];
    const float* b2   = (const float*)d_in[5];
    const float* W3   = (const float*)d_in[6];
    const float* b3   = (const float*)d_in[7];
    float* out = (float*)d_out;

    // workspace layout (floats):
    //   part   B_*NSPLIT*D_ = 2,621,440  (10.5 MB)
    //   pooled B_*D_        =    81,920
    //   hpart  KS_*B_*H1_   =   655,360
    float* ws     = (float*)d_ws;
    float* part   = ws;
    float* pooled = part + (size_t)B_ * NSPLIT * D_;
    float* hpart  = pooled + (size_t)B_ * D_;

    pool_partial<<<dim3(NSPLIT, B_), 320, 0, stream>>>(rep, blen, part);
    pool_reduce <<<dim3(5, B_), 64, 0, stream>>>(part, blen, pooled);
    mlp1_partial<<<dim3(NJT_, KS_), 512, 0, stream>>>(pooled, W1, hpart);
    mlp2        <<<dim3(NJT2_, B_), 512, 0, stream>>>(hpart, b1, W2, b2, out);
    mlp3        <<<B_, 64, 0, stream>>>(out, W3, b3, out);
}